// Round 10
// baseline (271.990 us; speedup 1.0000x reference)
//
#include <hip/hip_runtime.h>
#include <stdint.h>

typedef unsigned short u16;
typedef short bf16x8 __attribute__((ext_vector_type(8)));
typedef float f32x4 __attribute__((ext_vector_type(4)));
typedef float f32x16 __attribute__((ext_vector_type(16)));

#define B_ 4
#define S_ 2048
#define H_ 16
#define D_ 64
#define E_ 1024
#define M_ (B_ * S_)  // 8192

// round-to-nearest-even f32 -> bf16 (finite inputs only)
static __device__ __forceinline__ u16 f2bf(float f) {
  uint32_t u = __builtin_bit_cast(uint32_t, f);
  u += 0x7fffu + ((u >> 16) & 1u);
  return (u16)(u >> 16);
}
static __device__ __forceinline__ uint32_t pack2bf(float a, float b) {
  return (uint32_t)f2bf(a) | ((uint32_t)f2bf(b) << 16);
}
// packed f32,f32 -> bf16x2 in one instruction (lo = a, hi = b)
static __device__ __forceinline__ uint32_t cvt_pk_bf16(float a, float b) {
  uint32_t r;
  asm("v_cvt_pk_bf16_f32 %0, %1, %2" : "=v"(r) : "v"(a), "v"(b));
  return r;
}
// v_permlane32_swap_b32 a, b : swaps a.lanes[32:63] <-> b.lanes[0:31]
static __device__ __forceinline__ void pl32swap(uint32_t& a, uint32_t& b) {
  asm volatile("v_permlane32_swap_b32 %0, %1" : "+v"(a), "+v"(b));
}

// async global->LDS, 16B per lane; lds dst is wave-uniform base (HW adds lane*16)
static __device__ __forceinline__ void gld_lds16(const void* g, void* l) {
  __builtin_amdgcn_global_load_lds(
      (const __attribute__((address_space(1))) void*)(uintptr_t)g,
      (__attribute__((address_space(3))) void*)(uint32_t)(uintptr_t)l, 16, 0, 0);
}

// single launch: x (4096 blocks) + 4 weight matrices (512 blocks each);
// destination segments are contiguous in the workspace (xb, then wq..wo)
__global__ __launch_bounds__(256) void cvt_all(const float* __restrict__ x,
                                               const float* __restrict__ w0,
                                               const float* __restrict__ w1,
                                               const float* __restrict__ w2,
                                               const float* __restrict__ w3,
                                               u16* __restrict__ out) {
  const int bid = blockIdx.x;
  const float* src;
  int lb;          // local block within segment
  size_t obase;    // output base (u16 elements)
  if (bid < 4096) {
    src = x; lb = bid; obase = 0;
  } else {
    int t = bid - 4096;
    int s = t >> 9; lb = t & 511;
    src = s == 0 ? w0 : s == 1 ? w1 : s == 2 ? w2 : w3;
    obase = (size_t)M_ * E_ + (size_t)s * (E_ * E_);
  }
  int i = (lb * 256 + threadIdx.x) * 8;
  float4 a = *(const float4*)(src + i);
  float4 b = *(const float4*)(src + i + 4);
  struct __align__(16) U8 { u16 h[8]; } u;
  u.h[0] = f2bf(a.x); u.h[1] = f2bf(a.y); u.h[2] = f2bf(a.z); u.h[3] = f2bf(a.w);
  u.h[4] = f2bf(b.x); u.h[5] = f2bf(b.y); u.h[6] = f2bf(b.z); u.h[7] = f2bf(b.w);
  *(U8*)(out + obase + i) = u;
}

// 512-thread / 8-wave 256x128-tile GEMM, BK=32, phase-scheduled (T3/T4/T5):
// per K-step: {vmcnt(3) counted wait -> barrier -> 8 ds_read_b128 + issue
// stage(kk+2) (3 gld) -> lgkmcnt -> setprio(1) 16 MFMA setprio(0) -> barrier}.
// 4-deep LDS ring (96 KB), prefetch depth 2: the newest stage's 3 loads are
// NEVER drained in the main loop (vmcnt(3)); drain only at the final step.
// Buffer safety: stage(kk+2) writes buf[(kk+2)&3], last read at step kk-2,
// whose readers all passed two barriers before the stage is issued.
// LDS swizzle: group g stored at g^((row>>1)&3) -> b128 reads spread 16 lanes
// over 8 bank-slots = 2-way (free). Source pre-swizzled, read swizzled.
// Wave tile 64x64 (wm=wave>>1 in 0..3, wn=wave&1 in 0..1): per-wave acc[4][4]
// f32x4 and all three epilogues are IDENTICAL to the proven 128x128 kernel.
// KIND 0: bf16 out (transposed acc); KIND 1: f32 out; KIND 2: Vt layout.
template <int KIND, typename OutT>
static __device__ __forceinline__ void gemm256(const u16* __restrict__ A,
                                               const u16* __restrict__ W,
                                               const float* __restrict__ bias,
                                               OutT* __restrict__ C, int m0, int n0,
                                               float scale, u16* AsT, u16* BsT) {
  const int tid = threadIdx.x;
  const int wave = tid >> 6, lane = tid & 63;
  const int col16 = lane & 15, quad = lane >> 4;
  const int wm = wave >> 1, wn = wave & 1;   // wm 0..3, wn 0..1
  const int swz = (col16 >> 1) & 3;

  f32x4 acc[4][4] = {};

  auto stage = [&](int kk2, int buf) {
    const int k0 = kk2 * 32;
#pragma unroll
    for (int i = 0; i < 2; i++) {            // A: 1024 slots / 512 threads
      int s = i * 512 + tid;
      int ar = s >> 2, g = s & 3;
      gld_lds16(A + (size_t)(m0 + ar) * E_ + k0 + ((g ^ ((ar >> 1) & 3)) * 8),
                AsT + buf * 8192 + i * 4096 + wave * 512);
    }
    {                                         // B: 512 slots / 512 threads
      int br = tid >> 2, g = tid & 3;
      gld_lds16(W + (size_t)(n0 + br) * E_ + k0 + ((g ^ ((br >> 1) & 3)) * 8),
                BsT + buf * 4096 + wave * 512);
    }
  };

  stage(0, 0);
  stage(1, 1);

  const int NK = E_ / 32;  // 32 K-steps
  for (int kk = 0; kk < NK; kk++) {
    // counted wait: leave the newest stage's 3 loads in flight; the oldest
    // outstanding (stage(kk)) is forced complete. Last step drains.
    if (kk < NK - 1)
      asm volatile("s_waitcnt vmcnt(3)" ::: "memory");
    else
      asm volatile("s_waitcnt vmcnt(0)" ::: "memory");
    __builtin_amdgcn_s_barrier();   // all waves' stage(kk) now visible in LDS

    const u16* AC = AsT + (kk & 3) * 8192;
    const u16* BC = BsT + (kk & 3) * 4096;
    bf16x8 af[4], bw[4];
#pragma unroll
    for (int mt = 0; mt < 4; mt++)
      af[mt] = *(const bf16x8*)&AC[(wm * 64 + mt * 16 + col16) * 32 + ((quad ^ swz) * 8)];
#pragma unroll
    for (int nt = 0; nt < 4; nt++)
      bw[nt] = *(const bf16x8*)&BC[(wn * 64 + nt * 16 + col16) * 32 + ((quad ^ swz) * 8)];

    if (kk + 2 < NK) stage(kk + 2, (kk + 2) & 3);

    asm volatile("s_waitcnt lgkmcnt(0)" ::: "memory");
    __builtin_amdgcn_s_setprio(1);
#pragma unroll
    for (int a = 0; a < 4; a++)
#pragma unroll
      for (int b = 0; b < 4; b++) {
        if constexpr (KIND == 2)
          acc[a][b] = __builtin_amdgcn_mfma_f32_16x16x32_bf16(af[a], bw[b], acc[a][b], 0, 0, 0);
        else  // transposed: D[n][m], a = n-frag, b = m-frag
          acc[a][b] = __builtin_amdgcn_mfma_f32_16x16x32_bf16(bw[a], af[b], acc[a][b], 0, 0, 0);
      }
    __builtin_amdgcn_s_setprio(0);
    __builtin_amdgcn_s_barrier();
  }

  if constexpr (KIND == 2) {
    // normal acc: lane col = out-col (d), rows = 4 consecutive tokens -> Vt pack
#pragma unroll
    for (int a = 0; a < 4; a++) {
      int t = m0 + wm * 64 + a * 16 + quad * 4;     // token base (mult of 4)
      int bb = t >> 11, s = t & (S_ - 1);
#pragma unroll
      for (int b = 0; b < 4; b++) {
        int oc = n0 + wn * 64 + b * 16 + col16;     // E-col = h*64+d
        int h = oc >> 6, d = oc & 63;
        float bv = bias[oc];
        uint32_t lo = pack2bf(acc[a][b][0] + bv, acc[a][b][1] + bv);
        uint32_t hi = pack2bf(acc[a][b][2] + bv, acc[a][b][3] + bv);
        uint2 pk = {lo, hi};
        *(uint2*)&C[(((size_t)(bb * H_ + h) * D_ + d) * S_) + s] = pk;
      }
    }
  } else {
    // transposed acc: lane col16 = out-row, quad*4+e = 4 consecutive out-cols
#pragma unroll
    for (int b = 0; b < 4; b++) {
      int row = m0 + wm * 64 + b * 16 + col16;
#pragma unroll
      for (int a = 0; a < 4; a++) {
        int nc = n0 + wn * 64 + a * 16 + quad * 4;
        float4 bv = *(const float4*)&bias[nc];
        float v0 = (acc[a][b][0] + bv.x) * scale;
        float v1 = (acc[a][b][1] + bv.y) * scale;
        float v2 = (acc[a][b][2] + bv.z) * scale;
        float v3 = (acc[a][b][3] + bv.w) * scale;
        if constexpr (KIND == 0) {
          uint2 pk = {pack2bf(v0, v1), pack2bf(v2, v3)};
          *(uint2*)&((u16*)C)[(size_t)row * E_ + nc] = pk;
        } else {
          float4 pk = {v0, v1, v2, v3};
          *(float4*)&((float*)C)[(size_t)row * E_ + nc] = pk;
        }
      }
    }
  }
}

// fused QKV: grid 768 = 3 matrices x (32 m-panels x 8 n-panels), 1 block/CU,
// exactly 3 generations. XCD map: m-panel = (j&3)*8 + xcd (m fast) -> per-XCD
// A band 4x512KB = 2 MB L2-resident; concurrent B panels ~2 MB.
__global__ __launch_bounds__(512) void gemm_qkv(const u16* __restrict__ xb,
                                                const u16* __restrict__ wq, const u16* __restrict__ wk,
                                                const u16* __restrict__ wv,
                                                const float* __restrict__ bq, const float* __restrict__ bk,
                                                const float* __restrict__ bv,
                                                u16* __restrict__ Qb, u16* __restrict__ Kb,
                                                u16* __restrict__ Vtb) {
  __shared__ __align__(16) u16 AsT[4][256 * 32];  // 64 KB ring
  __shared__ __align__(16) u16 BsT[4][128 * 32];  // 32 KB ring
  const int L = blockIdx.x;            // 0..767
  const int xcd = L & 7, j = L >> 3;   // j 0..95
  const int mq = j & 3;                // m fast within XCD
  const int mat_n = j >> 2;            // 0..23
  const int mat = mat_n >> 3, npan = mat_n & 7;
  const int m0 = ((mq << 3) | xcd) * 256;
  const int n0 = npan * 128;
  if (mat == 0)
    gemm256<0, u16>(xb, wq, bq, Qb, m0, n0, 0.125f * 1.44269504f, &AsT[0][0], &BsT[0][0]);
  else if (mat == 1)
    gemm256<0, u16>(xb, wk, bk, Kb, m0, n0, 1.0f, &AsT[0][0], &BsT[0][0]);
  else
    gemm256<2, u16>(xb, wv, bv, Vtb, m0, n0, 1.0f, &AsT[0][0], &BsT[0][0]);
}

// grid 256 = 32 m x 8 n, exactly 1 generation at 1 block/CU
__global__ __launch_bounds__(512) void gemm_out(const u16* __restrict__ Ob,
                                                const u16* __restrict__ wob,
                                                const float* __restrict__ bo,
                                                float* __restrict__ out) {
  __shared__ __align__(16) u16 AsT[4][256 * 32];
  __shared__ __align__(16) u16 BsT[4][128 * 32];
  const int L = blockIdx.x;            // 0..255
  const int xcd = L & 7, j = L >> 3;   // 0..31
  const int mq = j & 3, npan = j >> 2; // m fast, n 0..7
  const int m0 = ((mq << 3) | xcd) * 256;
  const int n0 = npan * 128;
  gemm256<1, float>(Ob, wob, bo, out, m0, n0, 1.0f, &AsT[0][0], &BsT[0][0]);
}

// Flash attention, in-register softmax, 32x32x16 MFMA, 8 waves / 256 q-rows.
// Triple-buffered K/V staging with counted vmcnt: steady-state wait is
// vmcnt(2) (newest stage stays in flight), raw s_barrier (no implicit drain).
// XCD-aware block swizzle: the 8 q-tile blocks of one head get dispatch ids
// congruent mod 8 -> same XCD under the %8 round-robin -> that head's K/V is
// fetched into ONE L2 instead of eight.
__global__ __launch_bounds__(512) void flash_attn(const u16* __restrict__ Q,
                                                  const u16* __restrict__ K,
                                                  const u16* __restrict__ Vt,
                                                  u16* __restrict__ O) {
  __shared__ __align__(16) u16 Ks[3][64 * 64];
  __shared__ __align__(16) u16 Vs[3][64 * 64];
  // decode swizzled id: d = head%8 + 8*(qt + 8*(head/8)); bijective (512%8==0)
  const int d = blockIdx.x;
  const int xcd = d & 7;
  const int j = d >> 3;          // 0..63
  const int qt = j & 7;
  const int head = ((j >> 3) << 3) | xcd;  // 0..63
  const int h = head & 15, b = head >> 4;
  const int tid = threadIdx.x;
  const int wave = tid >> 6, lane = tid & 63;
  const int l31 = lane & 31, hi = lane >> 5;
  const int sw7 = l31 & 7;

  // staging: row-octet XOR swizzle so LDS(r,g) = global(r, g^(r&7));
  // 512 threads cover all 64 rows of one K tile + one V tile (1 gld each)
  const int srow = tid >> 3;                 // 0..63
  const int sgrp = (tid & 7) ^ (srow & 7);   // swizzled source group
  const u16* Kbase = K + ((size_t)(b * S_) * H_ + h) * D_;
  const u16* Vbase = Vt + ((size_t)(b * H_ + h) * D_) * S_;

  auto stage = [&](int kb, int buf) {
    gld_lds16(Kbase + (size_t)(kb * 64 + srow) * (H_ * D_) + sgrp * 8,
              &Ks[buf][wave * 512]);
    gld_lds16(Vbase + (size_t)srow * S_ + kb * 64 + sgrp * 8,
              &Vs[buf][wave * 512]);
  };

  stage(0, 0);
  stage(1, 1);

  // Q fragments (B-operand rows): q = qrow + l31, d = t*16 + hi*8 + j
  // pre-scaled by 1/sqrt(D)*log2(e) in the projection
  const int qrow = qt * 256 + wave * 32;
  bf16x8 qf[4];
  const u16* qp = Q + ((size_t)(b * S_ + qrow + l31) * H_ + h) * D_ + hi * 8;
#pragma unroll
  for (int t = 0; t < 4; t++) qf[t] = *(const bf16x8*)(qp + t * 16);

  f32x16 o_acc[2] = {};  // O[q][d], n-blocks of 32 d
  float l_sum = 0.f;     // per-lane partial of softmax denom for q = l31

  const int NT = S_ / 64;  // 32
  int cur = 0;
  for (int kb = 0; kb < NT; kb++) {
    // own stage(kb) loads done; stage(kb+1)'s 2 loads may stay in flight
    if (kb + 1 < NT)
      asm volatile("s_waitcnt vmcnt(2)" ::: "memory");
    else
      asm volatile("s_waitcnt vmcnt(0)" ::: "memory");
    __builtin_amdgcn_s_barrier();
    if (kb + 2 < NT) {
      int nb = cur + 2; if (nb >= 3) nb -= 3;
      stage(kb + 2, nb);
    }
    const u16* KsC = Ks[cur];
    const u16* VsC = Vs[cur];

#pragma unroll
    for (int kblk = 0; kblk < 2; kblk++) {
      // S^T[kv][q] over 32 kv rows; contraction D=64 in 4 chunks of 16
      const int krow = kblk * 32 + l31;
      const int ksw = krow & 7;
      f32x16 sacc = {};
      __builtin_amdgcn_s_setprio(1);
#pragma unroll
      for (int t = 0; t < 4; t++) {
        bf16x8 kf = *(const bf16x8*)&KsC[krow * 64 + (((2 * t + hi) ^ ksw) * 8)];
        sacc = __builtin_amdgcn_mfma_f32_32x32x16_bf16(kf, qf[t], sacc, 0, 0, 0);
      }
      __builtin_amdgcn_s_setprio(0);

      // p = exp2(s); per-lane l partial; pack row-pairs to bf16 words
      float p[16];
#pragma unroll
      for (int e = 0; e < 16; e++) p[e] = __builtin_amdgcn_exp2f(sacc[e]);
      float s0 = (p[0] + p[1]) + (p[2] + p[3]);
      float s1 = (p[4] + p[5]) + (p[6] + p[7]);
      float s2 = (p[8] + p[9]) + (p[10] + p[11]);
      float s3 = (p[12] + p[13]) + (p[14] + p[15]);
      l_sum += (s0 + s1) + (s2 + s3);
      uint32_t W[8];
#pragma unroll
      for (int i = 0; i < 8; i++) W[i] = cvt_pk_bf16(p[2 * i], p[2 * i + 1]);

      // build A-operand P fragments; PV immediately (V read from Vt rows in LDS)
#pragma unroll
      for (int kf2 = 0; kf2 < 2; kf2++) {
        uint32_t w0 = W[kf2 * 4 + 0], w1 = W[kf2 * 4 + 1];
        uint32_t w2 = W[kf2 * 4 + 2], w3 = W[kf2 * 4 + 3];
        pl32swap(w0, w2);  // lower: own/partner pair base+0..1 / +4..5
        pl32swap(w1, w3);  // (upper lanes get the +8.. variants)
        union { uint32_t w[4]; bf16x8 v; } u;
        u.w[0] = w0; u.w[1] = w1; u.w[2] = w2; u.w[3] = w3;
        const bf16x8 pa = u.v;
        const int kf = kblk * 2 + kf2;  // kv 16-chunk within the 64-block
        __builtin_amdgcn_s_setprio(1);
#pragma unroll
        for (int n = 0; n < 2; n++) {
          const int dr = n * 32 + l31;
          bf16x8 vf = *(const bf16x8*)&VsC[dr * 64 + (((2 * kf + hi) ^ sw7) * 8)];
          o_acc[n] = __builtin_amdgcn_mfma_f32_32x32x16_bf16(pa, vf, o_acc[n], 0, 0, 0);
        }
        __builtin_amdgcn_s_setprio(0);
      }
    }
    cur = (cur + 1 == 3) ? 0 : cur + 1;
  }

  // denom: lane covers half the kv rows for q=l31; partner (lane^32) the rest
  float l_tot = l_sum + __shfl_xor(l_sum, 32);
  float inv = 1.f / l_tot;

  // O[q][d]: rows q = (r&3)+8*(r>>2)+4*hi, col d = n*32 + l31 (coalesced)
#pragma unroll
  for (int r = 0; r < 16; r++) {
    const int ql = (r & 3) + 8 * (r >> 2) + 4 * hi;
    const float iq = __shfl(inv, ql);  // inv for row ql lives at lane ql
    u16* op = O + ((size_t)(b * S_ + qrow + ql) * H_ + h) * D_ + l31;
#pragma unroll
    for (int n = 0; n < 2; n++) op[n * 32] = f2bf(o_acc[n][r] * iq);
  }
}

extern "C" void kernel_launch(void* const* d_in, const int* in_sizes, int n_in,
                              void* d_out, int out_size, void* d_ws, size_t ws_size,
                              hipStream_t stream) {
  (void)in_sizes; (void)n_in; (void)out_size; (void)ws_size;
  const float* x  = (const float*)d_in[0];
  const float* Wq = (const float*)d_in[1];
  const float* bq = (const float*)d_in[2];
  const float* Wk = (const float*)d_in[3];
  const float* bk = (const float*)d_in[4];
  const float* Wv = (const float*)d_in[5];
  const float* bv = (const float*)d_in[6];
  const float* Wo = (const float*)d_in[7];
  const float* bo = (const float*)d_in[8];
  float* out = (float*)d_out;

  const size_t NX = (size_t)M_ * E_;
  const size_t NW = (size_t)E_ * E_;
  u16* xb  = (u16*)d_ws;
  u16* wqb = xb + NX;
  u16* wkb = wqb + NW;
  u16* wvb = wkb + NW;
  u16* wob = wvb + NW;
  u16* Qb  = wob + NW;
  u16* Kb  = Qb + NX;
  u16* Vtb = Kb + NX;
  u16* Ob  = Vtb + NX;

  cvt_all<<<4096 + 4 * 512, 256, 0, stream>>>(x, Wq, Wk, Wv, Wo, xb);

  gemm_qkv<<<768, 512, 0, stream>>>(xb, wqb, wkb, wvb, bq, bk, bv, Qb, Kb, Vtb);
  flash_attn<<<B_ * H_ * (S_ / 256), 512, 0, stream>>>(Qb, Kb, Vtb, Ob);
  gemm_out<<<256, 512, 0, stream>>>(Ob, wob, bo, out);
}

// Round 11
// 252.356 us; speedup vs baseline: 1.0778x; 1.0778x over previous
//
#include <hip/hip_runtime.h>
#include <stdint.h>

typedef unsigned short u16;
typedef short bf16x8 __attribute__((ext_vector_type(8)));
typedef float f32x4 __attribute__((ext_vector_type(4)));
typedef float f32x16 __attribute__((ext_vector_type(16)));

#define B_ 4
#define S_ 2048
#define H_ 16
#define D_ 64
#define E_ 1024
#define M_ (B_ * S_)  // 8192

// round-to-nearest-even f32 -> bf16 (finite inputs only)
static __device__ __forceinline__ u16 f2bf(float f) {
  uint32_t u = __builtin_bit_cast(uint32_t, f);
  u += 0x7fffu + ((u >> 16) & 1u);
  return (u16)(u >> 16);
}
static __device__ __forceinline__ uint32_t pack2bf(float a, float b) {
  return (uint32_t)f2bf(a) | ((uint32_t)f2bf(b) << 16);
}
// packed f32,f32 -> bf16x2 in one instruction (lo = a, hi = b)
static __device__ __forceinline__ uint32_t cvt_pk_bf16(float a, float b) {
  uint32_t r;
  asm("v_cvt_pk_bf16_f32 %0, %1, %2" : "=v"(r) : "v"(a), "v"(b));
  return r;
}
// v_permlane32_swap_b32 a, b : swaps a.lanes[32:63] <-> b.lanes[0:31]
static __device__ __forceinline__ void pl32swap(uint32_t& a, uint32_t& b) {
  asm volatile("v_permlane32_swap_b32 %0, %1" : "+v"(a), "+v"(b));
}

// async global->LDS, 16B per lane; lds dst is wave-uniform base (HW adds lane*16)
static __device__ __forceinline__ void gld_lds16(const void* g, void* l) {
  __builtin_amdgcn_global_load_lds(
      (const __attribute__((address_space(1))) void*)(uintptr_t)g,
      (__attribute__((address_space(3))) void*)(uint32_t)(uintptr_t)l, 16, 0, 0);
}

// single launch: x (4096 blocks) + 4 weight matrices (512 blocks each);
// destination segments are contiguous in the workspace (xb, then wq..wo)
__global__ __launch_bounds__(256) void cvt_all(const float* __restrict__ x,
                                               const float* __restrict__ w0,
                                               const float* __restrict__ w1,
                                               const float* __restrict__ w2,
                                               const float* __restrict__ w3,
                                               u16* __restrict__ out) {
  const int bid = blockIdx.x;
  const float* src;
  int lb;          // local block within segment
  size_t obase;    // output base (u16 elements)
  if (bid < 4096) {
    src = x; lb = bid; obase = 0;
  } else {
    int t = bid - 4096;
    int s = t >> 9; lb = t & 511;
    src = s == 0 ? w0 : s == 1 ? w1 : s == 2 ? w2 : w3;
    obase = (size_t)M_ * E_ + (size_t)s * (E_ * E_);
  }
  int i = (lb * 256 + threadIdx.x) * 8;
  float4 a = *(const float4*)(src + i);
  float4 b = *(const float4*)(src + i + 4);
  struct __align__(16) U8 { u16 h[8]; } u;
  u.h[0] = f2bf(a.x); u.h[1] = f2bf(a.y); u.h[2] = f2bf(a.z); u.h[3] = f2bf(a.w);
  u.h[4] = f2bf(b.x); u.h[5] = f2bf(b.y); u.h[6] = f2bf(b.z); u.h[7] = f2bf(b.w);
  *(U8*)(out + obase + i) = u;
}

// 256-thread / 4-wave 128x128-tile GEMM, BK=64, XOR-swizzled LDS.
// Double-buffered staging with counted wait: stage(k+1) issued right after the
// barrier (targets the buffer all waves just finished), waited via vmcnt(0) at
// the top of the next iteration -> the load round-trip hides under compute(k).
// 2 blocks/CU (64 KB LDS): co-resident block fills the barrier stalls (m114).
// KIND 0: bf16 out, transposed-acc epilogue (packed uint2 row-major stores)
// KIND 1: f32 out, transposed-acc epilogue (float4 stores)
// KIND 2: bf16 out -> Vt[b][h][d][s] (normal acc; 4 consecutive tokens packed)
template <int KIND, typename OutT>
static __device__ __forceinline__ void gemm128(const u16* __restrict__ A,
                                               const u16* __restrict__ W,
                                               const float* __restrict__ bias,
                                               OutT* __restrict__ C, int m0, int n0,
                                               float scale, u16* As, u16* Bs) {
  const int tid = threadIdx.x;
  const int wave = tid >> 6, lane = tid & 63;
  const int col16 = lane & 15, quad = lane >> 4;
  const int wm = wave >> 1, wn = wave & 1;

  f32x4 acc[4][4] = {};

  const int r0 = tid >> 3;                        // 0..31
  const int sg8 = ((tid & 7) ^ (r0 & 7)) * 8;     // swizzled source col-group
  const u16* ga = A + (size_t)(m0 + r0) * E_ + sg8;
  const u16* gb = W + (size_t)(n0 + r0) * E_ + sg8;
  u16* lA = As + wave * 512;
  u16* lB = Bs + wave * 512;

  auto stage = [&](int k0, int buf) {
#pragma unroll
    for (int i = 0; i < 4; i++) {
      gld_lds16(ga + (size_t)(i * 32) * E_ + k0, lA + buf * 8192 + i * 2048);
      gld_lds16(gb + (size_t)(i * 32) * E_ + k0, lB + buf * 8192 + i * 2048);
    }
  };

  stage(0, 0);
  const int NK = E_ / 64;  // 16
  for (int kk = 0; kk < NK; kk++) {
    // stage(kk)'s own 8 loads are the only outstanding VMEM; they had
    // compute(kk-1) to land (except kk=0: one exposed round trip per block)
    asm volatile("s_waitcnt vmcnt(0)" ::: "memory");
    __builtin_amdgcn_s_barrier();
    if (kk + 1 < NK) stage((kk + 1) * 64, (kk + 1) & 1);

    const u16* AsC = As + (kk & 1) * 8192;
    const u16* BsC = Bs + (kk & 1) * 8192;

    bf16x8 af[4][2], bw[4][2];
#pragma unroll
    for (int mt = 0; mt < 4; mt++)
#pragma unroll
      for (int ks = 0; ks < 2; ks++)
        af[mt][ks] = *(const bf16x8*)&AsC[(wm * 64 + mt * 16 + col16) * 64 +
                                          (((ks * 4 + quad) ^ (col16 & 7)) * 8)];
#pragma unroll
    for (int nt = 0; nt < 4; nt++)
#pragma unroll
      for (int ks = 0; ks < 2; ks++)
        bw[nt][ks] = *(const bf16x8*)&BsC[(wn * 64 + nt * 16 + col16) * 64 +
                                          (((ks * 4 + quad) ^ (col16 & 7)) * 8)];
#pragma unroll
    for (int ks = 0; ks < 2; ks++)
#pragma unroll
      for (int a = 0; a < 4; a++)
#pragma unroll
        for (int b = 0; b < 4; b++) {
          if constexpr (KIND == 2)
            acc[a][b] = __builtin_amdgcn_mfma_f32_16x16x32_bf16(af[a][ks], bw[b][ks], acc[a][b], 0, 0, 0);
          else  // transposed: D[n][m], a = n-frag, b = m-frag
            acc[a][b] = __builtin_amdgcn_mfma_f32_16x16x32_bf16(bw[a][ks], af[b][ks], acc[a][b], 0, 0, 0);
        }
  }

  if constexpr (KIND == 2) {
    // normal acc: lane col = out-col (d), rows = 4 consecutive tokens -> Vt pack
#pragma unroll
    for (int a = 0; a < 4; a++) {
      int t = m0 + wm * 64 + a * 16 + quad * 4;     // token base (mult of 4)
      int bb = t >> 11, s = t & (S_ - 1);
#pragma unroll
      for (int b = 0; b < 4; b++) {
        int oc = n0 + wn * 64 + b * 16 + col16;     // E-col = h*64+d
        int h = oc >> 6, d = oc & 63;
        float bv = bias[oc];
        uint32_t lo = pack2bf(acc[a][b][0] + bv, acc[a][b][1] + bv);
        uint32_t hi = pack2bf(acc[a][b][2] + bv, acc[a][b][3] + bv);
        uint2 pk = {lo, hi};
        *(uint2*)&C[(((size_t)(bb * H_ + h) * D_ + d) * S_) + s] = pk;
      }
    }
  } else {
    // transposed acc: lane col16 = out-row, quad*4+e = 4 consecutive out-cols
#pragma unroll
    for (int b = 0; b < 4; b++) {
      int row = m0 + wm * 64 + b * 16 + col16;
#pragma unroll
      for (int a = 0; a < 4; a++) {
        int nc = n0 + wn * 64 + a * 16 + quad * 4;
        float4 bv = *(const float4*)&bias[nc];
        float v0 = (acc[a][b][0] + bv.x) * scale;
        float v1 = (acc[a][b][1] + bv.y) * scale;
        float v2 = (acc[a][b][2] + bv.z) * scale;
        float v3 = (acc[a][b][3] + bv.w) * scale;
        if constexpr (KIND == 0) {
          uint2 pk = {pack2bf(v0, v1), pack2bf(v2, v3)};
          *(uint2*)&((u16*)C)[(size_t)row * E_ + nc] = pk;
        } else {
          float4 pk = {v0, v1, v2, v3};
          *(float4*)&((float*)C)[(size_t)row * E_ + nc] = pk;
        }
      }
    }
  }
}

// fused QKV: grid (24, 64). XCD-aware remap, (mat,n)-OUTER / m-INNER per XCD:
// xcd = L&7 keeps the m-band assignment (A band = 2 MB, L2-resident), and the
// per-XCD traversal order is mbx (weight panel) slow, mby fast -> active L2
// working set = A band (2 MB) + ONE B panel (0.25 MB); each B panel is pulled
// from L3 once instead of thrashing 6 MB of B through L2 per m-panel.
// Q epilogue folds 1/sqrt(D)*log2(e); V writes directly transposed to Vt.
__global__ __launch_bounds__(256) void gemm_qkv(const u16* __restrict__ xb,
                                                const u16* __restrict__ wq, const u16* __restrict__ wk,
                                                const u16* __restrict__ wv,
                                                const float* __restrict__ bq, const float* __restrict__ bk,
                                                const float* __restrict__ bv,
                                                u16* __restrict__ Qb, u16* __restrict__ Kb,
                                                u16* __restrict__ Vtb) {
  __shared__ __align__(16) u16 As[2][128 * 64];
  __shared__ __align__(16) u16 Bs[2][128 * 64];
  const int L = blockIdx.x + 24 * blockIdx.y;     // flat dispatch id, 0..1535
  const int xcd = L & 7;
  const int j = L >> 3;                           // 0..191 (per-XCD local index)
  const int mbx = j >> 3;                         // 0..23: (mat, n-panel), slow
  const int mby = ((j & 7) << 3) | xcd;           // 0..63: m-panel, fast
  const int mat = mbx >> 3;
  const int n0 = (mbx & 7) * 128;
  const int m0 = mby * 128;
  if (mat == 0)
    gemm128<0, u16>(xb, wq, bq, Qb, m0, n0, 0.125f * 1.44269504f, &As[0][0], &Bs[0][0]);
  else if (mat == 1)
    gemm128<0, u16>(xb, wk, bk, Kb, m0, n0, 1.0f, &As[0][0], &Bs[0][0]);
  else
    gemm128<2, u16>(xb, wv, bv, Vtb, m0, n0, 1.0f, &As[0][0], &Bs[0][0]);
}

// grid (8, 64): same remap principle (512 = 64*8): n-panel slow, m fast
__global__ __launch_bounds__(256) void gemm_out(const u16* __restrict__ Ob,
                                                const u16* __restrict__ wob,
                                                const float* __restrict__ bo,
                                                float* __restrict__ out) {
  __shared__ __align__(16) u16 As[2][128 * 64];
  __shared__ __align__(16) u16 Bs[2][128 * 64];
  const int L = blockIdx.x + 8 * blockIdx.y;      // 0..511
  const int xcd = L & 7;
  const int j = L >> 3;                           // 0..63
  const int obx = j >> 3;                         // 0..7: n-panel, slow
  const int oby = ((j & 7) << 3) | xcd;           // 0..63: m-panel, fast
  gemm128<1, float>(Ob, wob, bo, out, oby * 128, obx * 128, 1.0f,
                    &As[0][0], &Bs[0][0]);
}

// Flash attention, in-register softmax, 32x32x16 MFMA, 8 waves / 256 q-rows.
// Triple-buffered K/V staging with counted vmcnt: steady-state wait is
// vmcnt(2) (newest stage stays in flight), raw s_barrier (no implicit drain).
// XCD-aware block swizzle: the 8 q-tile blocks of one head get dispatch ids
// congruent mod 8 -> same XCD under the %8 round-robin -> that head's K/V is
// fetched into ONE L2 instead of eight.
__global__ __launch_bounds__(512) void flash_attn(const u16* __restrict__ Q,
                                                  const u16* __restrict__ K,
                                                  const u16* __restrict__ Vt,
                                                  u16* __restrict__ O) {
  __shared__ __align__(16) u16 Ks[3][64 * 64];
  __shared__ __align__(16) u16 Vs[3][64 * 64];
  // decode swizzled id: d = head%8 + 8*(qt + 8*(head/8)); bijective (512%8==0)
  const int d = blockIdx.x;
  const int xcd = d & 7;
  const int j = d >> 3;          // 0..63
  const int qt = j & 7;
  const int head = ((j >> 3) << 3) | xcd;  // 0..63
  const int h = head & 15, b = head >> 4;
  const int tid = threadIdx.x;
  const int wave = tid >> 6, lane = tid & 63;
  const int l31 = lane & 31, hi = lane >> 5;
  const int sw7 = l31 & 7;

  // staging: row-octet XOR swizzle so LDS(r,g) = global(r, g^(r&7));
  // 512 threads cover all 64 rows of one K tile + one V tile (1 gld each)
  const int srow = tid >> 3;                 // 0..63
  const int sgrp = (tid & 7) ^ (srow & 7);   // swizzled source group
  const u16* Kbase = K + ((size_t)(b * S_) * H_ + h) * D_;
  const u16* Vbase = Vt + ((size_t)(b * H_ + h) * D_) * S_;

  auto stage = [&](int kb, int buf) {
    gld_lds16(Kbase + (size_t)(kb * 64 + srow) * (H_ * D_) + sgrp * 8,
              &Ks[buf][wave * 512]);
    gld_lds16(Vbase + (size_t)srow * S_ + kb * 64 + sgrp * 8,
              &Vs[buf][wave * 512]);
  };

  stage(0, 0);
  stage(1, 1);

  // Q fragments (B-operand rows): q = qrow + l31, d = t*16 + hi*8 + j
  // pre-scaled by 1/sqrt(D)*log2(e) in the projection
  const int qrow = qt * 256 + wave * 32;
  bf16x8 qf[4];
  const u16* qp = Q + ((size_t)(b * S_ + qrow + l31) * H_ + h) * D_ + hi * 8;
#pragma unroll
  for (int t = 0; t < 4; t++) qf[t] = *(const bf16x8*)(qp + t * 16);

  f32x16 o_acc[2] = {};  // O[q][d], n-blocks of 32 d
  float l_sum = 0.f;     // per-lane partial of softmax denom for q = l31

  const int NT = S_ / 64;  // 32
  int cur = 0;
  for (int kb = 0; kb < NT; kb++) {
    // own stage(kb) loads done; stage(kb+1)'s 2 loads may stay in flight
    if (kb + 1 < NT)
      asm volatile("s_waitcnt vmcnt(2)" ::: "memory");
    else
      asm volatile("s_waitcnt vmcnt(0)" ::: "memory");
    __builtin_amdgcn_s_barrier();
    if (kb + 2 < NT) {
      int nb = cur + 2; if (nb >= 3) nb -= 3;
      stage(kb + 2, nb);
    }
    const u16* KsC = Ks[cur];
    const u16* VsC = Vs[cur];

#pragma unroll
    for (int kblk = 0; kblk < 2; kblk++) {
      // S^T[kv][q] over 32 kv rows; contraction D=64 in 4 chunks of 16
      const int krow = kblk * 32 + l31;
      const int ksw = krow & 7;
      f32x16 sacc = {};
      __builtin_amdgcn_s_setprio(1);
#pragma unroll
      for (int t = 0; t < 4; t++) {
        bf16x8 kf = *(const bf16x8*)&KsC[krow * 64 + (((2 * t + hi) ^ ksw) * 8)];
        sacc = __builtin_amdgcn_mfma_f32_32x32x16_bf16(kf, qf[t], sacc, 0, 0, 0);
      }
      __builtin_amdgcn_s_setprio(0);

      // p = exp2(s); per-lane l partial; pack row-pairs to bf16 words
      float p[16];
#pragma unroll
      for (int e = 0; e < 16; e++) p[e] = __builtin_amdgcn_exp2f(sacc[e]);
      float s0 = (p[0] + p[1]) + (p[2] + p[3]);
      float s1 = (p[4] + p[5]) + (p[6] + p[7]);
      float s2 = (p[8] + p[9]) + (p[10] + p[11]);
      float s3 = (p[12] + p[13]) + (p[14] + p[15]);
      l_sum += (s0 + s1) + (s2 + s3);
      uint32_t W[8];
#pragma unroll
      for (int i = 0; i < 8; i++) W[i] = cvt_pk_bf16(p[2 * i], p[2 * i + 1]);

      // build A-operand P fragments; PV immediately (V read from Vt rows in LDS)
#pragma unroll
      for (int kf2 = 0; kf2 < 2; kf2++) {
        uint32_t w0 = W[kf2 * 4 + 0], w1 = W[kf2 * 4 + 1];
        uint32_t w2 = W[kf2 * 4 + 2], w3 = W[kf2 * 4 + 3];
        pl32swap(w0, w2);  // lower: own/partner pair base+0..1 / +4..5
        pl32swap(w1, w3);  // (upper lanes get the +8.. variants)
        union { uint32_t w[4]; bf16x8 v; } u;
        u.w[0] = w0; u.w[1] = w1; u.w[2] = w2; u.w[3] = w3;
        const bf16x8 pa = u.v;
        const int kf = kblk * 2 + kf2;  // kv 16-chunk within the 64-block
        __builtin_amdgcn_s_setprio(1);
#pragma unroll
        for (int n = 0; n < 2; n++) {
          const int dr = n * 32 + l31;
          bf16x8 vf = *(const bf16x8*)&VsC[dr * 64 + (((2 * kf + hi) ^ sw7) * 8)];
          o_acc[n] = __builtin_amdgcn_mfma_f32_32x32x16_bf16(pa, vf, o_acc[n], 0, 0, 0);
        }
        __builtin_amdgcn_s_setprio(0);
      }
    }
    cur = (cur + 1 == 3) ? 0 : cur + 1;
  }

  // denom: lane covers half the kv rows for q=l31; partner (lane^32) the rest
  float l_tot = l_sum + __shfl_xor(l_sum, 32);
  float inv = 1.f / l_tot;

  // O[q][d]: rows q = (r&3)+8*(r>>2)+4*hi, col d = n*32 + l31 (coalesced)
#pragma unroll
  for (int r = 0; r < 16; r++) {
    const int ql = (r & 3) + 8 * (r >> 2) + 4 * hi;
    const float iq = __shfl(inv, ql);  // inv for row ql lives at lane ql
    u16* op = O + ((size_t)(b * S_ + qrow + ql) * H_ + h) * D_ + l31;
#pragma unroll
    for (int n = 0; n < 2; n++) op[n * 32] = f2bf(o_acc[n][r] * iq);
  }
}

extern "C" void kernel_launch(void* const* d_in, const int* in_sizes, int n_in,
                              void* d_out, int out_size, void* d_ws, size_t ws_size,
                              hipStream_t stream) {
  (void)in_sizes; (void)n_in; (void)out_size; (void)ws_size;
  const float* x  = (const float*)d_in[0];
  const float* Wq = (const float*)d_in[1];
  const float* bq = (const float*)d_in[2];
  const float* Wk = (const float*)d_in[3];
  const float* bk = (const float*)d_in[4];
  const float* Wv = (const float*)d_in[5];
  const float* bv = (const float*)d_in[6];
  const float* Wo = (const float*)d_in[7];
  const float* bo = (const float*)d_in[8];
  float* out = (float*)d_out;

  const size_t NX = (size_t)M_ * E_;
  const size_t NW = (size_t)E_ * E_;
  u16* xb  = (u16*)d_ws;
  u16* wqb = xb + NX;
  u16* wkb = wqb + NW;
  u16* wvb = wkb + NW;
  u16* wob = wvb + NW;
  u16* Qb  = wob + NW;
  u16* Kb  = Qb + NX;
  u16* Vtb = Kb + NX;
  u16* Ob  = Vtb + NX;

  cvt_all<<<4096 + 4 * 512, 256, 0, stream>>>(x, Wq, Wk, Wv, Wo, xb);

  gemm_qkv<<<dim3(24, 64), 256, 0, stream>>>(xb, wqb, wkb, wvb, bq, bk, bv, Qb, Kb, Vtb);
  flash_attn<<<B_ * H_ * (S_ / 256), 512, 0, stream>>>(Qb, Kb, Vtb, Ob);
  gemm_out<<<dim3(8, 64), 256, 0, stream>>>(Ob, wob, bo, out);
}